// Round 8
// baseline (46.218 us; speedup 1.0000x reference)
//
#include <hip/hip_runtime.h>
#include <hip/hip_bf16.h>

#define MM 64
#define KTOT 4096
#define NN 11008
#define PACKS 1376    // NN / 8
#define BN 128
#define NBLK 86       // NN / BN
#define KSPLIT 8
#define BKCHUNK 512   // KTOT / KSPLIT
#define BK 64         // k per step
#define NSTEP 8       // BKCHUNK / BK
#define NBLOCKS (NBLK * KSPLIT)  // 688

typedef float f32x16 __attribute__((ext_vector_type(16)));
typedef short bf16x8 __attribute__((ext_vector_type(8)));

__device__ __forceinline__ unsigned int f2bf(float f) {
    unsigned int b = __float_as_uint(f);
    return (b + 0x7FFFu + ((b >> 16) & 1u)) >> 16;   // RNE to bf16
}
__device__ __forceinline__ float bf2f(unsigned int h) {
    return __uint_as_float(h << 16);
}

// prep: 64 blocks (one per m row) x 256 threads.
// Converts x -> bf16 (xbf, linear [m][k]) and computes per-group row sums
// R[g][m] = sum_{k in group g} bf16(x[m][k])  (32 groups x 64 rows).
__global__ __launch_bounds__(256) void prep(const float* __restrict__ x,
                                            unsigned short* __restrict__ xbf,
                                            float* __restrict__ Rbuf) {
    const int m = blockIdx.x, t = threadIdx.x;     // t covers k = 16t..16t+15
    const float* src = x + m * KTOT + t * 16;
    unsigned int ob[8];
    float s = 0.f;
#pragma unroll
    for (int i = 0; i < 4; ++i) {
        const float4 v = reinterpret_cast<const float4*>(src)[i];
        const unsigned a = f2bf(v.x), b = f2bf(v.y), c = f2bf(v.z), d = f2bf(v.w);
        ob[i * 2]     = a | (b << 16);
        ob[i * 2 + 1] = c | (d << 16);
        s += bf2f(a) + bf2f(b) + bf2f(c) + bf2f(d);
    }
    uint4* dst = reinterpret_cast<uint4*>(xbf + m * KTOT + t * 16);
    dst[0] = make_uint4(ob[0], ob[1], ob[2], ob[3]);
    dst[1] = make_uint4(ob[4], ob[5], ob[6], ob[7]);
    // 8 threads (one 128-k group) reduce; lanes are 8-aligned within the wave
    s += __shfl_xor(s, 1);
    s += __shfl_xor(s, 2);
    s += __shfl_xor(s, 4);
    if ((t & 7) == 0) Rbuf[(t >> 3) * 64 + m] = s;   // group g = t>>3
}

// AWQ GEMM: 256 thr / 4 waves, wave = 64m x 32n, mfma_f32_32x32x16_bf16.
// B-operand built per-lane from TRANSPOSED packed qweight staging (qt) with
// the bf16 bias trick: (nib | 0x4300) == bf16(128+nib), exact. Per-group
// correction: ACC += s*P - s*(128+z)*R.
__global__ __launch_bounds__(256, 2) void awq_mfma(
    const unsigned short* __restrict__ xbf, const int* __restrict__ qw,
    const int* __restrict__ qz, const float* __restrict__ sc,
    const float* __restrict__ Rbuf, float* __restrict__ part)
{
    __shared__ __attribute__((aligned(16))) unsigned int qt[2][16][64]; // [cp][krow^swz]
    __shared__ __attribute__((aligned(16))) unsigned int xst[2][64][32]; // [m][k-dw swz]

    const int tid = threadIdx.x, wv = tid >> 6, l = tid & 63;
    const int bid = blockIdx.x;
    const int ks  = bid & 7;              // k-stripe == XCD (round-robin dispatch)
    const int bn  = bid >> 3;
    const int k00 = ks * BKCHUNK;
    const int l31 = l & 31, hi = l >> 5;

    // staging maps (block-cooperative, fully coalesced)
    const int qkrow = tid >> 2, qcq = (tid & 3) * 4;  // 64 k-rows x 4 dwords (uint4)
    const int xrow  = tid >> 2, xs0 = tid & 3;        // 64 m-rows, slots xs0 & xs0+4

    // lane compute constants
    const int myn  = wv * 32 + l31;                   // n within block tile
    const int cp   = myn >> 3;                        // pack-col in qt
    const int j    = myn & 7;                         // nibble col
    const int sh   = ((j >> 1) << 2) + ((j & 1) << 4);// AWQ nibble shift (validated)
    const int fsw  = (cp & 7) << 2;                   // qt k-swizzle
    const int ncol = bn * BN + myn;                   // global n

    const int* qsrc = qw + (k00 + qkrow) * PACKS + bn * 16 + qcq;
    const unsigned short* xsrc = xbf + xrow * KTOT + k00;

    uint4 qreg[2], xreg[2][2];
    float s_c, szb_c, s_nf = 0.f;
    int zz_n = 0;
    f32x16 accP[2];
    f32x16 ACC[2] = {};

    // prologue: step-0 staging regs + group-0 scale/zero
    qreg[0]    = *reinterpret_cast<const uint4*>(qsrc);
    xreg[0][0] = *reinterpret_cast<const uint4*>(xsrc + xs0 * 8);
    xreg[0][1] = *reinterpret_cast<const uint4*>(xsrc + (xs0 + 4) * 8);
    {
        const int g0 = k00 >> 7;
        const float s = sc[g0 * NN + ncol];
        const int  zz = qz[g0 * PACKS + (ncol >> 3)];
        s_c   = s;
        szb_c = s * (128.0f + (float)((zz >> sh) & 0xF));
    }

#pragma unroll
    for (int st = 0; st < NSTEP; ++st) {
        const int B = st & 1, P = B ^ 1;

        // prefetch next step's staging (stays in flight across the barrier)
        if (st + 1 < NSTEP) {
            qreg[P]    = *reinterpret_cast<const uint4*>(qsrc + (st + 1) * BK * PACKS);
            xreg[P][0] = *reinterpret_cast<const uint4*>(xsrc + (st + 1) * BK + xs0 * 8);
            xreg[P][1] = *reinterpret_cast<const uint4*>(xsrc + (st + 1) * BK + (xs0 + 4) * 8);
        }
        if ((st & 1) == 0) {
            // new group: zero P accumulators, prefetch next group's scale/zero
            accP[0] = (f32x16){};
            accP[1] = (f32x16){};
            if (st < 6) {
                const int gn = (k00 >> 7) + (st >> 1) + 1;
                s_nf = sc[gn * NN + ncol];
                zz_n = qz[gn * PACKS + (ncol >> 3)];
            }
        }

        // ---- staging writes ----
        {
            const unsigned int qv[4] = { qreg[B].x, qreg[B].y, qreg[B].z, qreg[B].w };
#pragma unroll
            for (int i = 0; i < 4; ++i) {
                const int cpw = qcq + i;
                qt[B][cpw][qkrow ^ ((cpw & 7) << 2)] = qv[i];
            }
            *reinterpret_cast<uint4*>(&xst[B][xrow][(xs0 ^ (xrow & 7)) << 2]) = xreg[B][0];
            *reinterpret_cast<uint4*>(&xst[B][xrow][((xs0 + 4) ^ (xrow & 7)) << 2]) = xreg[B][1];
        }

        // one barrier per step: drain LDS writes only, globals stay in flight
        asm volatile("s_waitcnt lgkmcnt(0)\n\ts_barrier" ::: "memory");

        // ---- 4 k-frags: build B per-lane from packed qt, MFMA against xst A ----
#pragma unroll
        for (int kf = 0; kf < 4; ++kf) {
            const int k0 = kf * 16 + hi * 8;
            const uint4 qa = *reinterpret_cast<const uint4*>(&qt[B][cp][k0 ^ fsw]);
            const uint4 qb = *reinterpret_cast<const uint4*>(&qt[B][cp][(k0 + 4) ^ fsw]);
            uint4 db;
            db.x = (((qa.x >> sh) & 0xFu) | (((qa.y >> sh) & 0xFu) << 16)) | 0x43004300u;
            db.y = (((qa.z >> sh) & 0xFu) | (((qa.w >> sh) & 0xFu) << 16)) | 0x43004300u;
            db.z = (((qb.x >> sh) & 0xFu) | (((qb.y >> sh) & 0xFu) << 16)) | 0x43004300u;
            db.w = (((qb.z >> sh) & 0xFu) | (((qb.w >> sh) & 0xFu) << 16)) | 0x43004300u;
            const bf16x8 bfr = __builtin_bit_cast(bf16x8, db);
#pragma unroll
            for (int mf = 0; mf < 2; ++mf) {
                const int row = mf * 32 + l31;
                const int col = ((kf * 2 + hi) ^ (row & 7)) << 2;
                const bf16x8 af = *reinterpret_cast<const bf16x8*>(&xst[B][row][col]);
                accP[mf] = __builtin_amdgcn_mfma_f32_32x32x16_bf16(af, bfr, accP[mf], 0, 0, 0);
            }
        }

        // ---- group end (every 2 steps): ACC += s*P - s*(128+z)*R ----
        if (st & 1) {
            const float* Rg = Rbuf + ((k00 >> 7) + (st >> 1)) * 64;
#pragma unroll
            for (int mf = 0; mf < 2; ++mf)
#pragma unroll
                for (int rq = 0; rq < 4; ++rq) {
                    const float4 r4 = *reinterpret_cast<const float4*>(
                        Rg + mf * 32 + rq * 8 + 4 * hi);
                    const float rr[4] = { r4.x, r4.y, r4.z, r4.w };
#pragma unroll
                    for (int r = 0; r < 4; ++r) {
                        const int reg = rq * 4 + r;
                        ACC[mf][reg] = fmaf(s_c, accP[mf][reg], ACC[mf][reg]);
                        ACC[mf][reg] = fmaf(-szb_c, rr[r], ACC[mf][reg]);
                    }
                }
            if (st < 7) {   // roll group scale/zero
                s_c   = s_nf;
                szb_c = s_nf * (128.0f + (float)((zz_n >> sh) & 0xF));
            }
        }
    }

    // ---- epilogue (C/D 32x32: col=l&31, row=(r&3)+8*(r>>2)+4*(l>>5)) ----
    float* pout = part + ks * (MM * NN) + ncol;
#pragma unroll
    for (int mf = 0; mf < 2; ++mf)
#pragma unroll
        for (int r = 0; r < 16; ++r) {
            const int m = mf * 32 + (r & 3) + 8 * (r >> 2) + 4 * hi;
            pout[m * NN] = ACC[mf][r];
        }
}

// reduce: out = bias + sum_ks part[ks]
__global__ __launch_bounds__(256) void reduce_k(const float* __restrict__ part,
                                                const float* __restrict__ bias,
                                                float* __restrict__ out) {
    const int t = blockIdx.x * 256 + threadIdx.x;   // float4 idx, 176128 total
    const int n = (t * 4) % NN;
    float4 s = reinterpret_cast<const float4*>(part)[t];
#pragma unroll
    for (int ks = 1; ks < KSPLIT; ++ks) {
        const float4 v = reinterpret_cast<const float4*>(part + ks * (MM * NN))[t];
        s.x += v.x; s.y += v.y; s.z += v.z; s.w += v.w;
    }
    const float4 b = *reinterpret_cast<const float4*>(bias + n);
    s.x += b.x; s.y += b.y; s.z += b.z; s.w += b.w;
    reinterpret_cast<float4*>(out)[t] = s;
}

extern "C" void kernel_launch(void* const* d_in, const int* in_sizes, int n_in,
                              void* d_out, int out_size, void* d_ws, size_t ws_size,
                              hipStream_t stream) {
    const float* x    = (const float*)d_in[0];
    const int*   qw   = (const int*)d_in[1];
    const int*   qz   = (const int*)d_in[2];
    const float* sc   = (const float*)d_in[3];
    const float* bias = (const float*)d_in[4];
    float* out = (float*)d_out;

    unsigned short* xbf = (unsigned short*)d_ws;                          // 512 KB
    float* Rbuf = (float*)((char*)d_ws + MM * KTOT * sizeof(unsigned short));      // 8 KB
    float* part = (float*)((char*)d_ws + MM * KTOT * sizeof(unsigned short) + 32 * 64 * sizeof(float));

    prep<<<dim3(MM), 256, 0, stream>>>(x, xbf, Rbuf);
    awq_mfma<<<dim3(NBLOCKS), 256, 0, stream>>>(xbf, qw, qz, sc, Rbuf, part);
    reduce_k<<<dim3(MM * NN / 4 / 256), 256, 0, stream>>>(part, bias, out);
}

// Round 9
// 38.287 us; speedup vs baseline: 1.2071x; 1.2071x over previous
//
#include <hip/hip_runtime.h>
#include <hip/hip_bf16.h>

#define MM 64
#define KTOT 4096
#define NN 11008
#define PACKS 1376    // NN / 8
#define BN 128
#define NBLK 86       // NN / BN
#define KSPLIT 8
#define BKCHUNK 512   // KTOT / KSPLIT
#define BK 64         // k per step
#define NSTEP 8       // BKCHUNK / BK
#define NBLOCKS (NBLK * KSPLIT)  // 688

typedef float f32x4 __attribute__((ext_vector_type(4)));
typedef short bf16x8 __attribute__((ext_vector_type(8)));

__device__ __forceinline__ unsigned int f2bf(float f) {
    unsigned int b = __float_as_uint(f);
    return (b + 0x7FFFu + ((b >> 16) & 1u)) >> 16;   // RNE to bf16
}
__device__ __forceinline__ float bf2f(unsigned int h) {
    return __uint_as_float(h << 16);
}

// prep: 256 blocks (64 m x 4 k-quarters) x 256 thr.
// xbf = bf16(x) linear [m][k]; Rbuf[g][m] = sum over group g of bf16(x[m][k]).
__global__ __launch_bounds__(256) void prep(const float* __restrict__ x,
                                            unsigned short* __restrict__ xbf,
                                            float* __restrict__ Rbuf) {
    const int m = blockIdx.x >> 2, kq = blockIdx.x & 3, t = threadIdx.x;
    const int k = kq * 1024 + t * 4;
    const float4 v = *reinterpret_cast<const float4*>(x + m * KTOT + k);
    const unsigned a = f2bf(v.x), b = f2bf(v.y), c = f2bf(v.z), d = f2bf(v.w);
    *reinterpret_cast<uint2*>(xbf + m * KTOT + k) =
        make_uint2(a | (b << 16), c | (d << 16));
    float s = bf2f(a) + bf2f(b) + bf2f(c) + bf2f(d);
    s += __shfl_xor(s, 1);
    s += __shfl_xor(s, 2);
    s += __shfl_xor(s, 4);
    s += __shfl_xor(s, 8);
    s += __shfl_xor(s, 16);                      // 32 lanes = one 128-k group
    if ((t & 31) == 0) Rbuf[(kq * 8 + (t >> 5)) * 64 + m] = s;
}

// AWQ GEMM: 512 thr / 8 waves, wave = 64m x 16n, mfma_f32_16x16x32_bf16.
// B built per-lane from transposed packed qt with the exact bias trick
// (nib|0x4300 == bf16(128+nib)); per-group: ACC += s*P - s*(128+z)*R.
__global__ __launch_bounds__(512, 4) void awq_mfma(
    const unsigned short* __restrict__ xbf, const int* __restrict__ qw,
    const int* __restrict__ qz, const float* __restrict__ sc,
    const float* __restrict__ Rbuf, float* __restrict__ part)
{
    __shared__ __attribute__((aligned(16))) unsigned int qt[2][16][68];  // [cp][k], pad->stride 68
    __shared__ __attribute__((aligned(16))) unsigned int xst[2][64][32]; // [m][k-dw swizzled]

    const int tid = threadIdx.x, wv = tid >> 6, l = tid & 63;
    const int bid = blockIdx.x;
    const int ks  = bid & 7;              // k-stripe == XCD (round-robin dispatch)
    const int bn  = bid >> 3;
    const int k00 = ks * BKCHUNK;
    const int l15 = l & 15, l4 = l >> 4;

    // block-cooperative staging maps (fully coalesced)
    const int qrow = tid >> 3, qc2 = (tid & 7) * 2;   // 64 k-rows x 16 dw (64B/row)
    const int xrow = tid >> 3, xsl = tid & 7;         // 64 m-rows x 8 slots of 16B

    // compute-lane constants
    const int nloc = wv * 16 + l15;                   // n within block tile
    const int cp   = nloc >> 3;                       // pack-col 0..15
    const int j    = nloc & 7;
    const int sh   = ((j >> 1) << 2) + ((j & 1) << 4);// AWQ nibble shift (validated)
    const int ncol = bn * BN + nloc;                  // global n

    const int* qsrc = qw + (k00 + qrow) * PACKS + bn * 16 + qc2;
    const unsigned short* xsrc = xbf + xrow * KTOT + k00 + xsl * 8;

    uint2 qreg[2];
    uint4 xreg[2];
    float s_c, szb_c, s_n = 0.f;
    int zz_n = 0;
    f32x4 accP[4], ACC[4] = {};

    // prologue
    qreg[0] = *reinterpret_cast<const uint2*>(qsrc);
    xreg[0] = *reinterpret_cast<const uint4*>(xsrc);
    {
        const int g0 = k00 >> 7;
        s_c = sc[g0 * NN + ncol];
        const int zz = qz[g0 * PACKS + (ncol >> 3)];
        szb_c = s_c * (128.0f + (float)((zz >> sh) & 0xF));
    }

#pragma unroll
    for (int st = 0; st < NSTEP; ++st) {
        const int B = st & 1, P = B ^ 1;

        // prefetch next step's staging (stays in flight across the barrier)
        if (st + 1 < NSTEP) {
            qreg[P] = *reinterpret_cast<const uint2*>(qsrc + (st + 1) * BK * PACKS);
            xreg[P] = *reinterpret_cast<const uint4*>(xsrc + (st + 1) * BK);
        }
        if ((st & 1) == 0) {   // new group: reset P, prefetch next scale/zero
            accP[0] = (f32x4){};
            accP[1] = (f32x4){};
            accP[2] = (f32x4){};
            accP[3] = (f32x4){};
            if (st < 6) {
                const int gn = (k00 >> 7) + (st >> 1) + 1;
                s_n  = sc[gn * NN + ncol];
                zz_n = qz[gn * PACKS + (ncol >> 3)];
            }
        }

        // staging writes: qt transposed (2 b32), xst swizzled (1 b128)
        qt[B][qc2][qrow]     = qreg[B].x;
        qt[B][qc2 + 1][qrow] = qreg[B].y;
        *reinterpret_cast<uint4*>(&xst[B][xrow][(xsl ^ (xrow & 7)) << 2]) = xreg[B];

        // one barrier per step: drain LDS only, globals stay in flight
        asm volatile("s_waitcnt lgkmcnt(0)\n\ts_barrier" ::: "memory");

        // ---- per 32-k fragment: build B from packed qt, MFMA vs xst A ----
#pragma unroll
        for (int kk = 0; kk < 2; ++kk) {
            const int k0 = kk * 32 + l4 * 8;
            const uint4 qa = *reinterpret_cast<const uint4*>(&qt[B][cp][k0]);
            const uint4 qb = *reinterpret_cast<const uint4*>(&qt[B][cp][k0 + 4]);
            uint4 db;
            db.x = (((qa.x >> sh) & 0xFu) | (((qa.y >> sh) & 0xFu) << 16)) | 0x43004300u;
            db.y = (((qa.z >> sh) & 0xFu) | (((qa.w >> sh) & 0xFu) << 16)) | 0x43004300u;
            db.z = (((qb.x >> sh) & 0xFu) | (((qb.y >> sh) & 0xFu) << 16)) | 0x43004300u;
            db.w = (((qb.z >> sh) & 0xFu) | (((qb.w >> sh) & 0xFu) << 16)) | 0x43004300u;
            const bf16x8 bfr = __builtin_bit_cast(bf16x8, db);
#pragma unroll
            for (int mt = 0; mt < 4; ++mt) {
                const int r = mt * 16 + l15;
                const int c = (kk * 16 + l4 * 4) ^ ((r & 7) << 2);
                const bf16x8 af = *reinterpret_cast<const bf16x8*>(&xst[B][r][c]);
                accP[mt] = __builtin_amdgcn_mfma_f32_16x16x32_bf16(af, bfr, accP[mt], 0, 0, 0);
            }
        }

        // ---- group end (every 2 steps): ACC += s*P - s*(128+z)*R ----
        if (st & 1) {
            const float* Rg = Rbuf + ((k00 >> 7) + (st >> 1)) * 64;
#pragma unroll
            for (int mt = 0; mt < 4; ++mt) {
                const float4 r4 = *reinterpret_cast<const float4*>(Rg + mt * 16 + l4 * 4);
                const float rr[4] = { r4.x, r4.y, r4.z, r4.w };
#pragma unroll
                for (int r = 0; r < 4; ++r) {
                    ACC[mt][r] = fmaf(s_c, accP[mt][r], ACC[mt][r]);
                    ACC[mt][r] = fmaf(-szb_c, rr[r], ACC[mt][r]);
                }
            }
            if (st < 7) {   // roll group scale/zero
                s_c   = s_n;
                szb_c = s_n * (128.0f + (float)((zz_n >> sh) & 0xF));
            }
        }
    }

    // ---- epilogue: plain stores (C/D: col=lane&15, row=(lane>>4)*4+r) ----
    float* pout = part + ks * (MM * NN) + bn * BN + wv * 16;
#pragma unroll
    for (int mt = 0; mt < 4; ++mt) {
        const int r0 = mt * 16 + l4 * 4;
#pragma unroll
        for (int r = 0; r < 4; ++r)
            pout[(r0 + r) * NN + l15] = ACC[mt][r];
    }
}

// reduce: out = bias + sum_ks part[ks]
__global__ __launch_bounds__(256) void reduce_k(const float* __restrict__ part,
                                                const float* __restrict__ bias,
                                                float* __restrict__ out) {
    const int t = blockIdx.x * 256 + threadIdx.x;   // float4 idx, 176128 total
    const int n = (t * 4) % NN;
    float4 s = reinterpret_cast<const float4*>(part)[t];
#pragma unroll
    for (int ks = 1; ks < KSPLIT; ++ks) {
        const float4 v = reinterpret_cast<const float4*>(part + ks * (MM * NN))[t];
        s.x += v.x; s.y += v.y; s.z += v.z; s.w += v.w;
    }
    const float4 b = *reinterpret_cast<const float4*>(bias + n);
    s.x += b.x; s.y += b.y; s.z += b.z; s.w += b.w;
    reinterpret_cast<float4*>(out)[t] = s;
}

extern "C" void kernel_launch(void* const* d_in, const int* in_sizes, int n_in,
                              void* d_out, int out_size, void* d_ws, size_t ws_size,
                              hipStream_t stream) {
    const float* x    = (const float*)d_in[0];
    const int*   qw   = (const int*)d_in[1];
    const int*   qz   = (const int*)d_in[2];
    const float* sc   = (const float*)d_in[3];
    const float* bias = (const float*)d_in[4];
    float* out = (float*)d_out;

    unsigned short* xbf = (unsigned short*)d_ws;                              // 512 KB
    float* Rbuf = (float*)((char*)d_ws + MM * KTOT * sizeof(unsigned short)); // 8 KB
    float* part = (float*)((char*)d_ws + MM * KTOT * sizeof(unsigned short)
                           + 32 * 64 * sizeof(float));                        // 22.5 MB

    prep<<<dim3(256), 256, 0, stream>>>(x, xbf, Rbuf);
    awq_mfma<<<dim3(NBLOCKS), 512, 0, stream>>>(xbf, qw, qz, sc, Rbuf, part);
    reduce_k<<<dim3(MM * NN / 4 / 256), 256, 0, stream>>>(part, bias, out);
}

// Round 10
// 33.993 us; speedup vs baseline: 1.3596x; 1.1263x over previous
//
#include <hip/hip_runtime.h>
#include <hip/hip_bf16.h>

#define MM 64
#define KTOT 4096
#define NN 11008
#define PACKS 1376    // NN / 8
#define BN 128
#define NBLK 86       // NN / BN
#define KSPLIT 8
#define BKCHUNK 512   // KTOT / KSPLIT
#define BK 64         // k per step
#define NBLOCKS (NBLK * KSPLIT)  // 688

typedef float f32x4 __attribute__((ext_vector_type(4)));
typedef short bf16x8 __attribute__((ext_vector_type(8)));

__device__ __forceinline__ unsigned int f2bf(float f) {
    unsigned int b = __float_as_uint(f);
    return (b + 0x7FFFu + ((b >> 16) & 1u)) >> 16;   // RNE to bf16
}
__device__ __forceinline__ float bf2f(unsigned int h) {
    return __uint_as_float(h << 16);
}

// prep: 256 blocks (64 m x 4 k-quarters) x 256 thr.
// xbf = bf16(x) linear [m][k]; Rbuf[g][m] = sum over group g of bf16(x[m][k]).
__global__ __launch_bounds__(256) void prep(const float* __restrict__ x,
                                            unsigned short* __restrict__ xbf,
                                            float* __restrict__ Rbuf) {
    const int m = blockIdx.x >> 2, kq = blockIdx.x & 3, t = threadIdx.x;
    const int k = kq * 1024 + t * 4;
    const float4 v = *reinterpret_cast<const float4*>(x + m * KTOT + k);
    const unsigned a = f2bf(v.x), b = f2bf(v.y), c = f2bf(v.z), d = f2bf(v.w);
    *reinterpret_cast<uint2*>(xbf + m * KTOT + k) =
        make_uint2(a | (b << 16), c | (d << 16));
    float s = bf2f(a) + bf2f(b) + bf2f(c) + bf2f(d);
    s += __shfl_xor(s, 1);
    s += __shfl_xor(s, 2);
    s += __shfl_xor(s, 4);
    s += __shfl_xor(s, 8);
    s += __shfl_xor(s, 16);                      // 32 lanes = one 128-k group
    if ((t & 31) == 0) Rbuf[(kq * 8 + (t >> 5)) * 64 + m] = s;
}

// AWQ GEMM, ROLLED K-loop (4 iterations x 2 steps) to keep code L1I-resident.
// Math identical to R9: bias-trick B-build from transposed packed qt,
// per-group correction ACC += s*P - s*(128+z)*R.
__global__ __launch_bounds__(512, 4) void awq_mfma(
    const unsigned short* __restrict__ xbf, const int* __restrict__ qw,
    const int* __restrict__ qz, const float* __restrict__ sc,
    const float* __restrict__ Rbuf, float* __restrict__ part)
{
    __shared__ __attribute__((aligned(16))) unsigned int qt[2][16][68];  // [cp][k], pad
    __shared__ __attribute__((aligned(16))) unsigned int xst[2][64][32]; // [m][k-dw swz]

    const int tid = threadIdx.x, wv = tid >> 6, l = tid & 63;
    const int bid = blockIdx.x;
    const int ks  = bid & 7;              // k-stripe == XCD (round-robin dispatch)
    const int bn  = bid >> 3;
    const int k00 = ks * BKCHUNK;
    const int l15 = l & 15, l4 = l >> 4;

    // block-cooperative staging maps (fully coalesced)
    const int qrow = tid >> 3, qc2 = (tid & 7) * 2;   // 64 k-rows x 16 dw (64B/row)
    const int xrow = tid >> 3, xsl = tid & 7;         // 64 m-rows x 8 slots of 16B

    // compute-lane constants
    const int nloc = wv * 16 + l15;
    const int cp   = nloc >> 3;
    const int j    = nloc & 7;
    const int sh   = ((j >> 1) << 2) + ((j & 1) << 4);// AWQ nibble shift (validated)
    const int ncol = bn * BN + nloc;

    const int qstride = BK * PACKS;                   // dwords per k-step
    const int* qp = qw + (k00 + qrow) * PACKS + bn * 16 + qc2;
    const unsigned short* xp = xbf + xrow * KTOT + k00 + xsl * 8;
    const int g0 = k00 >> 7;
    const float* Rg = Rbuf + g0 * 64;

    uint2 qreg0, qreg1;
    uint4 xreg0, xreg1;
    float s_c, szb_c, s_n = 0.f;
    int zz_n = 0;
    f32x4 accP[4], ACC[4] = {};

    // prologue
    qreg0 = *reinterpret_cast<const uint2*>(qp);
    xreg0 = *reinterpret_cast<const uint4*>(xp);
    s_c = sc[g0 * NN + ncol];
    {
        const int zz = qz[g0 * PACKS + (ncol >> 3)];
        szb_c = s_c * (128.0f + (float)((zz >> sh) & 0xF));
    }

#define COMPUTE(B) do {                                                       \
    _Pragma("unroll")                                                         \
    for (int kk = 0; kk < 2; ++kk) {                                          \
        const int k0 = kk * 32 + l4 * 8;                                      \
        const uint4 qa = *reinterpret_cast<const uint4*>(&qt[B][cp][k0]);     \
        const uint4 qb = *reinterpret_cast<const uint4*>(&qt[B][cp][k0 + 4]); \
        uint4 db;                                                             \
        db.x = (((qa.x >> sh) & 0xFu) | (((qa.y >> sh) & 0xFu) << 16)) | 0x43004300u; \
        db.y = (((qa.z >> sh) & 0xFu) | (((qa.w >> sh) & 0xFu) << 16)) | 0x43004300u; \
        db.z = (((qb.x >> sh) & 0xFu) | (((qb.y >> sh) & 0xFu) << 16)) | 0x43004300u; \
        db.w = (((qb.z >> sh) & 0xFu) | (((qb.w >> sh) & 0xFu) << 16)) | 0x43004300u; \
        const bf16x8 bfr = __builtin_bit_cast(bf16x8, db);                    \
        _Pragma("unroll")                                                     \
        for (int mt = 0; mt < 4; ++mt) {                                      \
            const int r = mt * 16 + l15;                                      \
            const int c = (kk * 16 + l4 * 4) ^ ((r & 7) << 2);                \
            const bf16x8 af = *reinterpret_cast<const bf16x8*>(&xst[B][r][c]);\
            accP[mt] = __builtin_amdgcn_mfma_f32_16x16x32_bf16(af, bfr, accP[mt], 0, 0, 0); \
        }                                                                     \
    }                                                                         \
} while (0)

#pragma clang loop unroll(disable)
    for (int it = 0; it < 4; ++it) {
        // ======== phase 0 (even step, buffer 0) ========
        qreg1 = *reinterpret_cast<const uint2*>(qp + qstride);     // always in-bounds
        xreg1 = *reinterpret_cast<const uint4*>(xp + BK);
        accP[0] = (f32x4){};
        accP[1] = (f32x4){};
        accP[2] = (f32x4){};
        accP[3] = (f32x4){};
        if (it < 3) {   // next group's scale/zero
            s_n  = sc[(g0 + it + 1) * NN + ncol];
            zz_n = qz[(g0 + it + 1) * PACKS + (ncol >> 3)];
        }
        qt[0][qc2][qrow]     = qreg0.x;
        qt[0][qc2 + 1][qrow] = qreg0.y;
        *reinterpret_cast<uint4*>(&xst[0][xrow][(xsl ^ (xrow & 7)) << 2]) = xreg0;
        asm volatile("s_waitcnt lgkmcnt(0)\n\ts_barrier" ::: "memory");
        COMPUTE(0);

        // ======== phase 1 (odd step, buffer 1) ========
        if (it < 3) {   // prefetch next even step (guarded: OOB at it=3)
            qreg0 = *reinterpret_cast<const uint2*>(qp + 2 * qstride);
            xreg0 = *reinterpret_cast<const uint4*>(xp + 2 * BK);
        }
        qt[1][qc2][qrow]     = qreg1.x;
        qt[1][qc2 + 1][qrow] = qreg1.y;
        *reinterpret_cast<uint4*>(&xst[1][xrow][(xsl ^ (xrow & 7)) << 2]) = xreg1;
        asm volatile("s_waitcnt lgkmcnt(0)\n\ts_barrier" ::: "memory");
        COMPUTE(1);

        // ---- group end: ACC += s*P - s*(128+z)*R ----
#pragma unroll
        for (int mt = 0; mt < 4; ++mt) {
            const float4 r4 = *reinterpret_cast<const float4*>(Rg + mt * 16 + l4 * 4);
            const float rr[4] = { r4.x, r4.y, r4.z, r4.w };
#pragma unroll
            for (int r = 0; r < 4; ++r) {
                ACC[mt][r] = fmaf(s_c, accP[mt][r], ACC[mt][r]);
                ACC[mt][r] = fmaf(-szb_c, rr[r], ACC[mt][r]);
            }
        }
        s_c   = s_n;    // stale at it=3, unused
        szb_c = s_n * (128.0f + (float)((zz_n >> sh) & 0xF));

        qp += 2 * qstride;
        xp += 2 * BK;
        Rg += 64;
    }
#undef COMPUTE

    // ---- epilogue: plain stores (C/D: col=lane&15, row=(lane>>4)*4+r) ----
    float* pout = part + ks * (MM * NN) + bn * BN + wv * 16;
#pragma unroll
    for (int mt = 0; mt < 4; ++mt) {
        const int r0 = mt * 16 + l4 * 4;
#pragma unroll
        for (int r = 0; r < 4; ++r)
            pout[(r0 + r) * NN + l15] = ACC[mt][r];
    }
}

// reduce: out = bias + sum_ks part[ks]
__global__ __launch_bounds__(256) void reduce_k(const float* __restrict__ part,
                                                const float* __restrict__ bias,
                                                float* __restrict__ out) {
    const int t = blockIdx.x * 256 + threadIdx.x;   // float4 idx, 176128 total
    const int n = (t * 4) % NN;
    float4 s = reinterpret_cast<const float4*>(part)[t];
#pragma unroll
    for (int ks = 1; ks < KSPLIT; ++ks) {
        const float4 v = reinterpret_cast<const float4*>(part + ks * (MM * NN))[t];
        s.x += v.x; s.y += v.y; s.z += v.z; s.w += v.w;
    }
    const float4 b = *reinterpret_cast<const float4*>(bias + n);
    s.x += b.x; s.y += b.y; s.z += b.z; s.w += b.w;
    reinterpret_cast<float4*>(out)[t] = s;
}

extern "C" void kernel_launch(void* const* d_in, const int* in_sizes, int n_in,
                              void* d_out, int out_size, void* d_ws, size_t ws_size,
                              hipStream_t stream) {
    const float* x    = (const float*)d_in[0];
    const int*   qw   = (const int*)d_in[1];
    const int*   qz   = (const int*)d_in[2];
    const float* sc   = (const float*)d_in[3];
    const float* bias = (const float*)d_in[4];
    float* out = (float*)d_out;

    unsigned short* xbf = (unsigned short*)d_ws;                              // 512 KB
    float* Rbuf = (float*)((char*)d_ws + MM * KTOT * sizeof(unsigned short)); // 8 KB
    float* part = (float*)((char*)d_ws + MM * KTOT * sizeof(unsigned short)
                           + 32 * 64 * sizeof(float));                        // 22.5 MB

    prep<<<dim3(256), 256, 0, stream>>>(x, xbf, Rbuf);
    awq_mfma<<<dim3(NBLOCKS), 512, 0, stream>>>(xbf, qw, qz, sc, Rbuf, part);
    reduce_k<<<dim3(MM * NN / 4 / 256), 256, 0, stream>>>(part, bias, out);
}